// Round 18
// baseline (298.184 us; speedup 1.0000x reference)
//
#include <hip/hip_runtime.h>

#define NCOL 64
#define BSH 8                 // 256 dst nodes per bucket
#define NBMAX 512             // padded bucket count (scan width)
#define EPB 2048              // edges per P1 block
#define P2CAP 6144            // LDS out-stage entries (bucket avg 4096, +32 sigma)

typedef __attribute__((ext_vector_type(8))) short bf16x8;
typedef __attribute__((ext_vector_type(4))) float f32x4;

// ---------------- bf16 helpers (RNE pack, bit-shift unpack) ----------------

__device__ __forceinline__ unsigned int bf16pair(float a, float b) {
  unsigned int ua = __float_as_uint(a), ub = __float_as_uint(b);
  ua = (ua + 0x7FFFu + ((ua >> 16) & 1u)) >> 16;
  ub = (ub + 0x7FFFu + ((ub >> 16) & 1u)) >> 16;
  return (ub << 16) | ua;
}
__device__ __forceinline__ float bf_lo(unsigned int v) { return __uint_as_float(v << 16); }
__device__ __forceinline__ float bf_hi(unsigned int v) { return __uint_as_float(v & 0xFFFF0000u); }
__device__ __forceinline__ unsigned short bfs(float x) {  // RNE f32->bf16 bits
  unsigned int u = __float_as_uint(x);
  u = (u + 0x7FFFu + ((u >> 16) & 1u)) >> 16;
  return (unsigned short)u;
}

// ---------------- P1: block-local counting sort of edges by dst bucket ----------------
// Entry pack: (dst&255)<<17 | src   (src < 2^17 on this problem: n = 100000)

__global__ __launch_bounds__(256) void bin_p1(const int* __restrict__ src,
                                              const int* __restrict__ dst,
                                              unsigned int* __restrict__ ent,
                                              int* __restrict__ blockOff,
                                              int ne, int nb) {
  __shared__ int hist[NBMAX];
  __shared__ int base[NBMAX];
  __shared__ int part[256];
  __shared__ unsigned int stage[EPB];
  int tid = threadIdx.x;
  int e0 = blockIdx.x * EPB;
  int cnt = min(EPB, ne - e0);

  for (int i = tid; i < NBMAX; i += 256) hist[i] = 0;
  __syncthreads();
  for (int i = tid; i < cnt; i += 256) {
    int d = dst[e0 + i];
    atomicAdd(&hist[d >> BSH], 1);
  }
  __syncthreads();

  int a0 = hist[2 * tid], a1 = hist[2 * tid + 1];
  int s = a0 + a1;
  part[tid] = s;
  __syncthreads();
  for (int d = 1; d < 256; d <<= 1) {
    int v = (tid >= d) ? part[tid - d] : 0;
    __syncthreads();
    part[tid] += v;
    __syncthreads();
  }
  int off = part[tid] - s;
  base[2 * tid] = off;
  base[2 * tid + 1] = off + a0;
  __syncthreads();

  for (int b = tid; b < nb; b += 256) blockOff[(size_t)blockIdx.x * nb + b] = base[b];
  for (int i = tid; i < NBMAX; i += 256) hist[i] = base[i];
  __syncthreads();

  for (int i = tid; i < cnt; i += 256) {
    int d = dst[e0 + i];
    int sv = src[e0 + i];
    unsigned int e = ((unsigned int)(d & ((1 << BSH) - 1)) << 17) | (unsigned int)sv;
    int p = atomicAdd(&hist[d >> BSH], 1);
    stage[p] = e;
  }
  __syncthreads();
  for (int i = tid; i < cnt; i += 256) ent[e0 + i] = stage[i];
}

// ---------------- degree from binned entries (LDS counters, coalesced writes) ----------------

__global__ __launch_bounds__(256) void deg_bin(const unsigned int* __restrict__ ent,
                                               const int* __restrict__ blockOff,
                                               int* __restrict__ degi,
                                               int n, int ne, int nb, int nblk) {
  __shared__ int cnt[256];
  int b = blockIdx.x;
  int tid = threadIdx.x;
  cnt[tid] = 0;
  __syncthreads();
  for (int blk = tid; blk < nblk; blk += 256) {
    int e0 = blk * EPB;
    int bcnt = min(EPB, ne - e0);
    int st = blockOff[(size_t)blk * nb + b];
    int en = (b + 1 < nb) ? blockOff[(size_t)blk * nb + b + 1] : bcnt;
    for (int i = st; i < en; ++i) {
      unsigned int e = ent[e0 + i];
      atomicAdd(&cnt[e >> 17], 1);
    }
  }
  __syncthreads();
  int node = (b << BSH) + tid;
  if (node < n) degi[node] = cnt[tid];
}

__global__ void dinv_kernel(const int* __restrict__ degi, float* __restrict__ dinv, int n) {
  int i = blockIdx.x * blockDim.x + threadIdx.x;
  if (i < n) dinv[i] = rsqrtf((float)degi[i] + 1.0f);
}

// ---------------- graph-run boundaries (batch is SORTED -> no atomics) ----------------

__global__ void bounds_kernel(const int* __restrict__ batch, int* __restrict__ startg,
                              int* __restrict__ endg, int n) {
  int i = blockIdx.x * blockDim.x + threadIdx.x;
  if (i >= n) return;
  int b = batch[i];
  if (i == 0) {
    startg[b] = 0;
  } else {
    int bp = batch[i - 1];
    if (b != bp) { startg[b] = i; endg[bp] = i; }
  }
  if (i == n - 1) endg[b] = n;
}

// ---------------- 3-pass exclusive scan of degrees -> rowptr[0..n] ----------------

#define SCAN_C 8

__global__ void scan_part(const int* __restrict__ degi, int* __restrict__ tsum,
                          int n, int nthreads) {
  int t = blockIdx.x * blockDim.x + threadIdx.x;
  if (t >= nthreads) return;
  int lo = t * SCAN_C, hi = min(lo + SCAN_C, n);
  int s = 0;
  for (int i = lo; i < hi; ++i) s += degi[i];
  tsum[t] = s;
}

__global__ void scan_mid(int* __restrict__ tsum, int* __restrict__ toff, int nthreads) {
  __shared__ int part[1024];
  int t = threadIdx.x;
  int chunk = (nthreads + 1023) >> 10;
  int lo = t * chunk, hi = min(lo + chunk, nthreads);
  int s = 0;
  for (int i = lo; i < hi; ++i) s += tsum[i];
  part[t] = s;
  __syncthreads();
  for (int d = 1; d < 1024; d <<= 1) {
    int v = (t >= d) ? part[t - d] : 0;
    __syncthreads();
    part[t] += v;
    __syncthreads();
  }
  int off = part[t] - s;
  for (int i = lo; i < hi; ++i) { toff[i] = off; off += tsum[i]; }
}

__global__ void scan_fill(const int* __restrict__ degi, const int* __restrict__ toff,
                          int* __restrict__ rowptr, int n, int nthreads) {
  int t = blockIdx.x * blockDim.x + threadIdx.x;
  if (t >= nthreads) return;
  int lo = t * SCAN_C, hi = min(lo + SCAN_C, n);
  int off = toff[t];
  for (int i = lo; i < hi; ++i) {
    rowptr[i] = off;
    off += degi[i];
  }
  if (hi == n) rowptr[n] = off;
}

// ---------------- P2: bucket-local LDS scatter -> node-grouped CSR ----------------

__global__ __launch_bounds__(256) void bin_p2(const unsigned int* __restrict__ ent,
                                              const int* __restrict__ blockOff,
                                              const int* __restrict__ rowptr,
                                              int* __restrict__ csr_src,
                                              int n, int ne, int nb, int nblk) {
  __shared__ int cur[256];
  __shared__ int outS[P2CAP];
  int b = blockIdx.x;
  int tid = threadIdx.x;
  int node0 = b << BSH;
  int node1 = min(node0 + 256, n);
  int bucketBase = rowptr[node0];
  int bucketCnt = rowptr[node1] - bucketBase;
  int node = node0 + tid;
  cur[tid] = (node < node1) ? (rowptr[node] - bucketBase) : 0;
  __syncthreads();
  for (int blk = tid; blk < nblk; blk += 256) {
    int e0 = blk * EPB;
    int bcnt = min(EPB, ne - e0);
    int st = blockOff[(size_t)blk * nb + b];
    int en = (b + 1 < nb) ? blockOff[(size_t)blk * nb + b + 1] : bcnt;
    for (int i = st; i < en; ++i) {
      unsigned int e = ent[e0 + i];
      int dL = e >> 17;
      int sv = (int)(e & 0x1FFFFu);
      int p = atomicAdd(&cur[dL], 1);
      if (p < P2CAP) outS[p] = sv;
      else csr_src[bucketBase + p] = sv;   // rare overflow fallback
    }
  }
  __syncthreads();
  int lim = min(bucketCnt, P2CAP);
  for (int i = tid; i < lim; i += 256) csr_src[bucketBase + i] = outS[i];
}

// ---------------- MFMA GEMM -> bf16 messages ----------------
// mfma_f32_16x16x32_bf16. Block = 64 rows x 64 cols, 4 waves; wave w owns
// cols 16w..16w+15 and 4 row-tiles of 16 (layouts per guide §3, m89).

template<int K>
__global__ __launch_bounds__(256, 8) void gemm_mfma(
    const float* __restrict__ X, const float* __restrict__ W,
    const float* __restrict__ dinv, unsigned int* __restrict__ Ybf, int n) {
  __shared__ unsigned short YS[64][64];
  int tid = threadIdx.x;
  int w = tid >> 6;          // wave id -> col group
  int l = tid & 63;
  int lr = l & 15;           // A-row within tile / B,D col
  int lk = l >> 4;           // k group
  int rows0 = blockIdx.x * 64;

  // B fragments (held in registers for the whole kernel)
  bf16x8 bfrag[K / 32];
#pragma unroll
  for (int s = 0; s < K / 32; ++s) {
#pragma unroll
    for (int j = 0; j < 8; ++j) {
      int k = s * 32 + lk * 8 + j;
      bfrag[s][j] = (short)bfs(W[(size_t)k * NCOL + 16 * w + lr]);
    }
  }

  f32x4 acc[4];
#pragma unroll
  for (int rt = 0; rt < 4; ++rt) acc[rt] = (f32x4){0.f, 0.f, 0.f, 0.f};

#pragma unroll
  for (int rt = 0; rt < 4; ++rt) {
    int row = min(rows0 + rt * 16 + lr, n - 1);
    const float* xr = X + (size_t)row * K + lk * 8;
#pragma unroll
    for (int s = 0; s < K / 32; ++s) {
      float4 x0 = *reinterpret_cast<const float4*>(xr + s * 32);
      float4 x1 = *reinterpret_cast<const float4*>(xr + s * 32 + 4);
      bf16x8 af;
      af[0] = (short)bfs(x0.x); af[1] = (short)bfs(x0.y);
      af[2] = (short)bfs(x0.z); af[3] = (short)bfs(x0.w);
      af[4] = (short)bfs(x1.x); af[5] = (short)bfs(x1.y);
      af[6] = (short)bfs(x1.z); af[7] = (short)bfs(x1.w);
      acc[rt] = __builtin_amdgcn_mfma_f32_16x16x32_bf16(af, bfrag[s], acc[rt], 0, 0, 0);
    }
  }

  // epilogue: scale by dinv, pack bf16 into LDS tile
#pragma unroll
  for (int rt = 0; rt < 4; ++rt) {
#pragma unroll
    for (int j = 0; j < 4; ++j) {
      int row = rt * 16 + lk * 4 + j;
      float d = dinv[min(rows0 + row, n - 1)];
      YS[row][16 * w + lr] = bfs(acc[rt][j] * d);
    }
  }
  __syncthreads();

  // coalesced copy: 64 rows x 8 uint4
  const uint4* ys4 = reinterpret_cast<const uint4*>(&YS[0][0]);
  for (int idx = tid; idx < 512; idx += 256) {
    int row = idx >> 3;
    int gr = rows0 + row;
    if (gr < n)
      reinterpret_cast<uint4*>(Ybf + (size_t)gr * 32)[idx & 7] = ys4[idx];
  }
}

// ---------------- CSR gather-aggregate over bf16 messages ----------------
// 8-lane GROUP per dst node; lane-local accumulation (no cross-lane reduce).
// 4x unrolled edge loop -> 32 independent 128B gathers in flight per wave.
// POOL variant: skip H write; wave-reduce same-graph rows (batch sorted ->
// almost always uniform) and atomicAdd once per wave into pool[g].

template<bool RELU, bool POOL>
__global__ __launch_bounds__(256) void aggregate(
    const int* __restrict__ rowptr, const int* __restrict__ csr_src,
    const uint4* __restrict__ Ybf4, const float* __restrict__ dinv,
    const float* __restrict__ bias, float* __restrict__ H,
    const int* __restrict__ batch, float* __restrict__ pool, int n) {
  int nd = (blockIdx.x * blockDim.x + threadIdx.x) >> 3;
  if (nd >= n) return;
  int l = threadIdx.x & 7;    // uint4 slot within row (cols 8l..8l+8)
  int lo = rowptr[nd], hi = rowptr[nd + 1];

  // init accumulators from self-loop row
  uint4 vs = Ybf4[(size_t)nd * 8 + l];
  float a0 = bf_lo(vs.x), a1 = bf_hi(vs.x);
  float a2 = bf_lo(vs.y), a3 = bf_hi(vs.y);
  float a4 = bf_lo(vs.z), a5 = bf_hi(vs.z);
  float a6 = bf_lo(vs.w), a7 = bf_hi(vs.w);

  int p = lo;
  for (; p + 3 < hi; p += 4) {   // 4 edges in flight per group
    int s0 = csr_src[p];
    int s1 = csr_src[p + 1];
    int s2 = csr_src[p + 2];
    int s3 = csr_src[p + 3];
    uint4 v0 = Ybf4[(size_t)s0 * 8 + l];
    uint4 v1 = Ybf4[(size_t)s1 * 8 + l];
    uint4 v2 = Ybf4[(size_t)s2 * 8 + l];
    uint4 v3 = Ybf4[(size_t)s3 * 8 + l];
    a0 += bf_lo(v0.x); a1 += bf_hi(v0.x);
    a2 += bf_lo(v0.y); a3 += bf_hi(v0.y);
    a4 += bf_lo(v0.z); a5 += bf_hi(v0.z);
    a6 += bf_lo(v0.w); a7 += bf_hi(v0.w);
    a0 += bf_lo(v1.x); a1 += bf_hi(v1.x);
    a2 += bf_lo(v1.y); a3 += bf_hi(v1.y);
    a4 += bf_lo(v1.z); a5 += bf_hi(v1.z);
    a6 += bf_lo(v1.w); a7 += bf_hi(v1.w);
    a0 += bf_lo(v2.x); a1 += bf_hi(v2.x);
    a2 += bf_lo(v2.y); a3 += bf_hi(v2.y);
    a4 += bf_lo(v2.z); a5 += bf_hi(v2.z);
    a6 += bf_lo(v2.w); a7 += bf_hi(v2.w);
    a0 += bf_lo(v3.x); a1 += bf_hi(v3.x);
    a2 += bf_lo(v3.y); a3 += bf_hi(v3.y);
    a4 += bf_lo(v3.z); a5 += bf_hi(v3.z);
    a6 += bf_lo(v3.w); a7 += bf_hi(v3.w);
  }
  for (; p < hi; ++p) {
    int s = csr_src[p];
    uint4 v = Ybf4[(size_t)s * 8 + l];
    a0 += bf_lo(v.x); a1 += bf_hi(v.x);
    a2 += bf_lo(v.y); a3 += bf_hi(v.y);
    a4 += bf_lo(v.z); a5 += bf_hi(v.z);
    a6 += bf_lo(v.w); a7 += bf_hi(v.w);
  }

  float d = dinv[nd];
  float4 b0 = *reinterpret_cast<const float4*>(bias + l * 8);
  float4 b1 = *reinterpret_cast<const float4*>(bias + l * 8 + 4);
  float4 o0, o1;
  o0.x = fmaf(d, a0, b0.x); o0.y = fmaf(d, a1, b0.y);
  o0.z = fmaf(d, a2, b0.z); o0.w = fmaf(d, a3, b0.w);
  o1.x = fmaf(d, a4, b1.x); o1.y = fmaf(d, a5, b1.y);
  o1.z = fmaf(d, a6, b1.z); o1.w = fmaf(d, a7, b1.w);
  if (RELU) {
    o0.x = fmaxf(o0.x, 0.f); o0.y = fmaxf(o0.y, 0.f);
    o0.z = fmaxf(o0.z, 0.f); o0.w = fmaxf(o0.w, 0.f);
    o1.x = fmaxf(o1.x, 0.f); o1.y = fmaxf(o1.y, 0.f);
    o1.z = fmaxf(o1.z, 0.f); o1.w = fmaxf(o1.w, 0.f);
  }

  if (!POOL) {
    float* hr = H + (size_t)nd * NCOL + l * 8;
    *reinterpret_cast<float4*>(hr) = o0;
    *reinterpret_cast<float4*>(hr + 4) = o1;
  } else {
    int gg = batch[nd];
    // wave covers 8 consecutive nodes; batch sorted -> usually one graph
    int waveFirstNd = (blockIdx.x * blockDim.x + (threadIdx.x & ~63)) >> 3;
    bool full = (waveFirstNd + 8 <= n);
    int g0 = __builtin_amdgcn_readfirstlane(gg);
    bool uni = full && __all(gg == g0);
    if (uni) {
#pragma unroll
      for (int m = 8; m < 64; m <<= 1) {
        o0.x += __shfl_xor(o0.x, m); o0.y += __shfl_xor(o0.y, m);
        o0.z += __shfl_xor(o0.z, m); o0.w += __shfl_xor(o0.w, m);
        o1.x += __shfl_xor(o1.x, m); o1.y += __shfl_xor(o1.y, m);
        o1.z += __shfl_xor(o1.z, m); o1.w += __shfl_xor(o1.w, m);
      }
      if ((threadIdx.x & 63) < 8) {
        float* pr = pool + (size_t)g0 * NCOL + l * 8;
        atomicAdd(pr + 0, o0.x); atomicAdd(pr + 1, o0.y);
        atomicAdd(pr + 2, o0.z); atomicAdd(pr + 3, o0.w);
        atomicAdd(pr + 4, o1.x); atomicAdd(pr + 5, o1.y);
        atomicAdd(pr + 6, o1.z); atomicAdd(pr + 7, o1.w);
      }
    } else {
      float* pr = pool + (size_t)gg * NCOL + l * 8;
      atomicAdd(pr + 0, o0.x); atomicAdd(pr + 1, o0.y);
      atomicAdd(pr + 2, o0.z); atomicAdd(pr + 3, o0.w);
      atomicAdd(pr + 4, o1.x); atomicAdd(pr + 5, o1.y);
      atomicAdd(pr + 6, o1.z); atomicAdd(pr + 7, o1.w);
    }
  }
}

// ---------------- final tiny GEMM: out = (pool/cnt) @ Wl + bl ----------------

__global__ void final_kernel(const float* __restrict__ pool, const int* __restrict__ startg,
                             const int* __restrict__ endg, const float* __restrict__ Wl,
                             const float* __restrict__ bl, float* __restrict__ out, int ng) {
  int t = threadIdx.x;
  if (t >= ng * 6) return;
  int g = t / 6, o = t % 6;
  float cntf = (float)(endg[g] - startg[g]);
  float inv = 1.0f / fmaxf(cntf, 1.0f);
  float s = 0.f;
#pragma unroll
  for (int c = 0; c < NCOL; ++c) s += pool[(size_t)g * NCOL + c] * Wl[c * 6 + o];
  out[t] = fmaf(s, inv, bl[o]);
}

// ---------------- launch ----------------

extern "C" void kernel_launch(void* const* d_in, const int* in_sizes, int n_in,
                              void* d_out, int out_size, void* d_ws, size_t ws_size,
                              hipStream_t stream) {
  const float* x    = (const float*)d_in[0];
  const int*   ei   = (const int*)d_in[1];
  const int*   batch= (const int*)d_in[2];
  const float* W1   = (const float*)d_in[3];
  const float* b1   = (const float*)d_in[4];
  const float* W2   = (const float*)d_in[5];
  const float* b2   = (const float*)d_in[6];
  const float* Wl   = (const float*)d_in[7];
  const float* bl   = (const float*)d_in[8];
  float* out = (float*)d_out;

  int n  = in_sizes[0] / 128;   // 100000
  int ne = in_sizes[1] / 2;     // 1600000
  int ng = out_size / 6;        // 64
  const int* srcI = ei;
  const int* dstI = ei + ne;

  int nb   = (n + 255) >> BSH;            // 391 buckets
  int nblk = (ne + EPB - 1) / EPB;        // 782 P1 blocks

  char* w = (char*)d_ws;
  size_t o = 0;
  auto take = [&](size_t bytes) -> char* {
    char* p = w + o;
    o = (o + bytes + 255) & ~(size_t)255;
    return p;
  };
  float*        dinv    = (float*)take((size_t)n * 4);
  int*          degi    = (int*)  take((size_t)n * 4);
  int*          rowptr  = (int*)  take((size_t)(n + 1) * 4);
  int*          csr_src = (int*)  take((size_t)ne * 4);
  unsigned int* ent     = (unsigned int*)take((size_t)ne * 4);
  int*          blockOff= (int*)  take((size_t)nblk * nb * 4);
  unsigned int* Ybf     = (unsigned int*)take((size_t)n * (NCOL / 2) * 4);
  float*        H       = (float*)take((size_t)n * NCOL * 4);
  float*        pool    = (float*)take(4096 * 4);
  int*          startg  = (int*)  take(64 * 4);
  int*          endg    = (int*)  take(64 * 4);
  int*          tsum    = (int*)  take(16384 * 4);
  int*          toff    = (int*)  take(16384 * 4);

  hipMemsetAsync(pool, 0, 4096 * 4, stream);
  hipMemsetAsync(startg, 0, 64 * 4, stream);
  hipMemsetAsync(endg, 0, 64 * 4, stream);

  int nb256 = (n + 255) / 256;
  int nthreads = (n + SCAN_C - 1) / SCAN_C;
  int nbScan = (nthreads + 255) / 256;

  // CSR build via two-phase LDS binning (all global writes coalesced)
  bin_p1<<<nblk, 256, 0, stream>>>(srcI, dstI, ent, blockOff, ne, nb);
  deg_bin<<<nb, 256, 0, stream>>>(ent, blockOff, degi, n, ne, nb, nblk);
  bounds_kernel<<<nb256, 256, 0, stream>>>(batch, startg, endg, n);
  dinv_kernel<<<nb256, 256, 0, stream>>>(degi, dinv, n);
  scan_part<<<nbScan, 256, 0, stream>>>(degi, tsum, n, nthreads);
  scan_mid<<<1, 1024, 0, stream>>>(tsum, toff, nthreads);
  scan_fill<<<nbScan, 256, 0, stream>>>(degi, toff, rowptr, n, nthreads);
  bin_p2<<<nb, 256, 0, stream>>>(ent, blockOff, rowptr, csr_src, n, ne, nb, nblk);

  int nbAgg = (n * 8 + 255) / 256;   // 8 lanes per node
  int nbGemm = (n + 63) / 64;

  // layer 1: Ybf = bf16((x@W1)*dinv) ; H = relu(dinv*(Y_self + sum Y[src]) + b1)
  gemm_mfma<128><<<nbGemm, 256, 0, stream>>>(x, W1, dinv, Ybf, n);
  aggregate<true, false><<<nbAgg, 256, 0, stream>>>(rowptr, csr_src, (const uint4*)Ybf,
                                                    dinv, b1, H, batch, pool, n);

  // layer 2: Ybf = bf16((H@W2)*dinv) ; pool[g] += dinv*(Y_self + sum Y[src]) + b2
  gemm_mfma<64><<<nbGemm, 256, 0, stream>>>(H, W2, dinv, Ybf, n);
  aggregate<false, true><<<nbAgg, 256, 0, stream>>>(rowptr, csr_src, (const uint4*)Ybf,
                                                    dinv, b2, H, batch, pool, n);

  // head (mean + tiny GEMM)
  final_kernel<<<1, 384, 0, stream>>>(pool, startg, endg, Wl, bl, out, ng);
}

// Round 19
// 298.004 us; speedup vs baseline: 1.0006x; 1.0006x over previous
//
#include <hip/hip_runtime.h>

#define NCOL 64
#define BSH 8                 // 256 dst nodes per bucket
#define NBMAX 512             // padded bucket count (scan width)
#define EPB 2048              // edges per P1 block
#define P2CAP 6144            // LDS out-stage entries (bucket avg 4096, +32 sigma)

typedef __attribute__((ext_vector_type(8))) short bf16x8;
typedef __attribute__((ext_vector_type(4))) float f32x4;

// ---------------- bf16 helpers (RNE pack, bit-shift unpack) ----------------

__device__ __forceinline__ unsigned int bf16pair(float a, float b) {
  unsigned int ua = __float_as_uint(a), ub = __float_as_uint(b);
  ua = (ua + 0x7FFFu + ((ua >> 16) & 1u)) >> 16;
  ub = (ub + 0x7FFFu + ((ub >> 16) & 1u)) >> 16;
  return (ub << 16) | ua;
}
__device__ __forceinline__ float bf_lo(unsigned int v) { return __uint_as_float(v << 16); }
__device__ __forceinline__ float bf_hi(unsigned int v) { return __uint_as_float(v & 0xFFFF0000u); }
__device__ __forceinline__ unsigned short bfs(float x) {  // RNE f32->bf16 bits
  unsigned int u = __float_as_uint(x);
  u = (u + 0x7FFFu + ((u >> 16) & 1u)) >> 16;
  return (unsigned short)u;
}

// ---------------- P1: block-local counting sort of edges by dst bucket ----------------
// Entry pack: (dst&255)<<17 | src   (src < 2^17 on this problem: n = 100000)

__global__ __launch_bounds__(256) void bin_p1(const int* __restrict__ src,
                                              const int* __restrict__ dst,
                                              unsigned int* __restrict__ ent,
                                              int* __restrict__ blockOff,
                                              int ne, int nb) {
  __shared__ int hist[NBMAX];
  __shared__ int base[NBMAX];
  __shared__ int part[256];
  __shared__ unsigned int stage[EPB];
  int tid = threadIdx.x;
  int e0 = blockIdx.x * EPB;
  int cnt = min(EPB, ne - e0);

  for (int i = tid; i < NBMAX; i += 256) hist[i] = 0;
  __syncthreads();
  for (int i = tid; i < cnt; i += 256) {
    int d = dst[e0 + i];
    atomicAdd(&hist[d >> BSH], 1);
  }
  __syncthreads();

  int a0 = hist[2 * tid], a1 = hist[2 * tid + 1];
  int s = a0 + a1;
  part[tid] = s;
  __syncthreads();
  for (int d = 1; d < 256; d <<= 1) {
    int v = (tid >= d) ? part[tid - d] : 0;
    __syncthreads();
    part[tid] += v;
    __syncthreads();
  }
  int off = part[tid] - s;
  base[2 * tid] = off;
  base[2 * tid + 1] = off + a0;
  __syncthreads();

  for (int b = tid; b < nb; b += 256) blockOff[(size_t)blockIdx.x * nb + b] = base[b];
  for (int i = tid; i < NBMAX; i += 256) hist[i] = base[i];
  __syncthreads();

  for (int i = tid; i < cnt; i += 256) {
    int d = dst[e0 + i];
    int sv = src[e0 + i];
    unsigned int e = ((unsigned int)(d & ((1 << BSH) - 1)) << 17) | (unsigned int)sv;
    int p = atomicAdd(&hist[d >> BSH], 1);
    stage[p] = e;
  }
  __syncthreads();
  for (int i = tid; i < cnt; i += 256) ent[e0 + i] = stage[i];
}

// ---------------- degree from binned entries (LDS counters, coalesced writes) ----------------

__global__ __launch_bounds__(256) void deg_bin(const unsigned int* __restrict__ ent,
                                               const int* __restrict__ blockOff,
                                               int* __restrict__ degi,
                                               int n, int ne, int nb, int nblk) {
  __shared__ int cnt[256];
  int b = blockIdx.x;
  int tid = threadIdx.x;
  cnt[tid] = 0;
  __syncthreads();
  for (int blk = tid; blk < nblk; blk += 256) {
    int e0 = blk * EPB;
    int bcnt = min(EPB, ne - e0);
    int st = blockOff[(size_t)blk * nb + b];
    int en = (b + 1 < nb) ? blockOff[(size_t)blk * nb + b + 1] : bcnt;
    for (int i = st; i < en; ++i) {
      unsigned int e = ent[e0 + i];
      atomicAdd(&cnt[e >> 17], 1);
    }
  }
  __syncthreads();
  int node = (b << BSH) + tid;
  if (node < n) degi[node] = cnt[tid];
}

__global__ void dinv_kernel(const int* __restrict__ degi, float* __restrict__ dinv, int n) {
  int i = blockIdx.x * blockDim.x + threadIdx.x;
  if (i < n) dinv[i] = rsqrtf((float)degi[i] + 1.0f);
}

// ---------------- graph-run boundaries (batch is SORTED -> no atomics) ----------------

__global__ void bounds_kernel(const int* __restrict__ batch, int* __restrict__ startg,
                              int* __restrict__ endg, int n) {
  int i = blockIdx.x * blockDim.x + threadIdx.x;
  if (i >= n) return;
  int b = batch[i];
  if (i == 0) {
    startg[b] = 0;
  } else {
    int bp = batch[i - 1];
    if (b != bp) { startg[b] = i; endg[bp] = i; }
  }
  if (i == n - 1) endg[b] = n;
}

// ---------------- 3-pass exclusive scan of degrees -> rowptr[0..n] ----------------

#define SCAN_C 8

__global__ void scan_part(const int* __restrict__ degi, int* __restrict__ tsum,
                          int n, int nthreads) {
  int t = blockIdx.x * blockDim.x + threadIdx.x;
  if (t >= nthreads) return;
  int lo = t * SCAN_C, hi = min(lo + SCAN_C, n);
  int s = 0;
  for (int i = lo; i < hi; ++i) s += degi[i];
  tsum[t] = s;
}

__global__ void scan_mid(int* __restrict__ tsum, int* __restrict__ toff, int nthreads) {
  __shared__ int part[1024];
  int t = threadIdx.x;
  int chunk = (nthreads + 1023) >> 10;
  int lo = t * chunk, hi = min(lo + chunk, nthreads);
  int s = 0;
  for (int i = lo; i < hi; ++i) s += tsum[i];
  part[t] = s;
  __syncthreads();
  for (int d = 1; d < 1024; d <<= 1) {
    int v = (t >= d) ? part[t - d] : 0;
    __syncthreads();
    part[t] += v;
    __syncthreads();
  }
  int off = part[t] - s;
  for (int i = lo; i < hi; ++i) { toff[i] = off; off += tsum[i]; }
}

__global__ void scan_fill(const int* __restrict__ degi, const int* __restrict__ toff,
                          int* __restrict__ rowptr, int n, int nthreads) {
  int t = blockIdx.x * blockDim.x + threadIdx.x;
  if (t >= nthreads) return;
  int lo = t * SCAN_C, hi = min(lo + SCAN_C, n);
  int off = toff[t];
  for (int i = lo; i < hi; ++i) {
    rowptr[i] = off;
    off += degi[i];
  }
  if (hi == n) rowptr[n] = off;
}

// ---------------- P2: bucket-local LDS scatter -> node-grouped CSR ----------------

__global__ __launch_bounds__(256) void bin_p2(const unsigned int* __restrict__ ent,
                                              const int* __restrict__ blockOff,
                                              const int* __restrict__ rowptr,
                                              int* __restrict__ csr_src,
                                              int n, int ne, int nb, int nblk) {
  __shared__ int cur[256];
  __shared__ int outS[P2CAP];
  int b = blockIdx.x;
  int tid = threadIdx.x;
  int node0 = b << BSH;
  int node1 = min(node0 + 256, n);
  int bucketBase = rowptr[node0];
  int bucketCnt = rowptr[node1] - bucketBase;
  int node = node0 + tid;
  cur[tid] = (node < node1) ? (rowptr[node] - bucketBase) : 0;
  __syncthreads();
  for (int blk = tid; blk < nblk; blk += 256) {
    int e0 = blk * EPB;
    int bcnt = min(EPB, ne - e0);
    int st = blockOff[(size_t)blk * nb + b];
    int en = (b + 1 < nb) ? blockOff[(size_t)blk * nb + b + 1] : bcnt;
    for (int i = st; i < en; ++i) {
      unsigned int e = ent[e0 + i];
      int dL = e >> 17;
      int sv = (int)(e & 0x1FFFFu);
      int p = atomicAdd(&cur[dL], 1);
      if (p < P2CAP) outS[p] = sv;
      else csr_src[bucketBase + p] = sv;   // rare overflow fallback
    }
  }
  __syncthreads();
  int lim = min(bucketCnt, P2CAP);
  for (int i = tid; i < lim; i += 256) csr_src[bucketBase + i] = outS[i];
}

// ---------------- MFMA GEMM -> bf16 messages ----------------
// mfma_f32_16x16x32_bf16. Block = 64 rows x 64 cols, 4 waves; wave w owns
// cols 16w..16w+15 and 4 row-tiles of 16 (layouts per guide §3, m89).

template<int K>
__global__ __launch_bounds__(256, 8) void gemm_mfma(
    const float* __restrict__ X, const float* __restrict__ W,
    const float* __restrict__ dinv, unsigned int* __restrict__ Ybf, int n) {
  __shared__ unsigned short YS[64][64];
  int tid = threadIdx.x;
  int w = tid >> 6;          // wave id -> col group
  int l = tid & 63;
  int lr = l & 15;           // A-row within tile / B,D col
  int lk = l >> 4;           // k group
  int rows0 = blockIdx.x * 64;

  // B fragments (held in registers for the whole kernel)
  bf16x8 bfrag[K / 32];
#pragma unroll
  for (int s = 0; s < K / 32; ++s) {
#pragma unroll
    for (int j = 0; j < 8; ++j) {
      int k = s * 32 + lk * 8 + j;
      bfrag[s][j] = (short)bfs(W[(size_t)k * NCOL + 16 * w + lr]);
    }
  }

  f32x4 acc[4];
#pragma unroll
  for (int rt = 0; rt < 4; ++rt) acc[rt] = (f32x4){0.f, 0.f, 0.f, 0.f};

#pragma unroll
  for (int rt = 0; rt < 4; ++rt) {
    int row = min(rows0 + rt * 16 + lr, n - 1);
    const float* xr = X + (size_t)row * K + lk * 8;
#pragma unroll
    for (int s = 0; s < K / 32; ++s) {
      float4 x0 = *reinterpret_cast<const float4*>(xr + s * 32);
      float4 x1 = *reinterpret_cast<const float4*>(xr + s * 32 + 4);
      bf16x8 af;
      af[0] = (short)bfs(x0.x); af[1] = (short)bfs(x0.y);
      af[2] = (short)bfs(x0.z); af[3] = (short)bfs(x0.w);
      af[4] = (short)bfs(x1.x); af[5] = (short)bfs(x1.y);
      af[6] = (short)bfs(x1.z); af[7] = (short)bfs(x1.w);
      acc[rt] = __builtin_amdgcn_mfma_f32_16x16x32_bf16(af, bfrag[s], acc[rt], 0, 0, 0);
    }
  }

  // epilogue: scale by dinv, pack bf16 into LDS tile
#pragma unroll
  for (int rt = 0; rt < 4; ++rt) {
#pragma unroll
    for (int j = 0; j < 4; ++j) {
      int row = rt * 16 + lk * 4 + j;
      float d = dinv[min(rows0 + row, n - 1)];
      YS[row][16 * w + lr] = bfs(acc[rt][j] * d);
    }
  }
  __syncthreads();

  // coalesced copy: 64 rows x 8 uint4
  const uint4* ys4 = reinterpret_cast<const uint4*>(&YS[0][0]);
  for (int idx = tid; idx < 512; idx += 256) {
    int row = idx >> 3;
    int gr = rows0 + row;
    if (gr < n)
      reinterpret_cast<uint4*>(Ybf + (size_t)gr * 32)[idx & 7] = ys4[idx];
  }
}

// ---------------- layer-1 aggregate: H = relu(dinv*(self + sum) + b) ----------------
// EXACT R17 structure (separate function, no pool code in the body, so its
// codegen is not perturbed by the pool variant - R18 lesson, guide rule #19).

__global__ __launch_bounds__(256) void aggregate_relu(
    const int* __restrict__ rowptr, const int* __restrict__ csr_src,
    const uint4* __restrict__ Ybf4, const float* __restrict__ dinv,
    const float* __restrict__ bias, float* __restrict__ H, int n) {
  int nd = (blockIdx.x * blockDim.x + threadIdx.x) >> 3;
  if (nd >= n) return;
  int l = threadIdx.x & 7;
  int lo = rowptr[nd], hi = rowptr[nd + 1];

  uint4 vs = Ybf4[(size_t)nd * 8 + l];
  float a0 = bf_lo(vs.x), a1 = bf_hi(vs.x);
  float a2 = bf_lo(vs.y), a3 = bf_hi(vs.y);
  float a4 = bf_lo(vs.z), a5 = bf_hi(vs.z);
  float a6 = bf_lo(vs.w), a7 = bf_hi(vs.w);

  int p = lo;
  for (; p + 3 < hi; p += 4) {
    int s0 = csr_src[p];
    int s1 = csr_src[p + 1];
    int s2 = csr_src[p + 2];
    int s3 = csr_src[p + 3];
    uint4 v0 = Ybf4[(size_t)s0 * 8 + l];
    uint4 v1 = Ybf4[(size_t)s1 * 8 + l];
    uint4 v2 = Ybf4[(size_t)s2 * 8 + l];
    uint4 v3 = Ybf4[(size_t)s3 * 8 + l];
    a0 += bf_lo(v0.x); a1 += bf_hi(v0.x);
    a2 += bf_lo(v0.y); a3 += bf_hi(v0.y);
    a4 += bf_lo(v0.z); a5 += bf_hi(v0.z);
    a6 += bf_lo(v0.w); a7 += bf_hi(v0.w);
    a0 += bf_lo(v1.x); a1 += bf_hi(v1.x);
    a2 += bf_lo(v1.y); a3 += bf_hi(v1.y);
    a4 += bf_lo(v1.z); a5 += bf_hi(v1.z);
    a6 += bf_lo(v1.w); a7 += bf_hi(v1.w);
    a0 += bf_lo(v2.x); a1 += bf_hi(v2.x);
    a2 += bf_lo(v2.y); a3 += bf_hi(v2.y);
    a4 += bf_lo(v2.z); a5 += bf_hi(v2.z);
    a6 += bf_lo(v2.w); a7 += bf_hi(v2.w);
    a0 += bf_lo(v3.x); a1 += bf_hi(v3.x);
    a2 += bf_lo(v3.y); a3 += bf_hi(v3.y);
    a4 += bf_lo(v3.z); a5 += bf_hi(v3.z);
    a6 += bf_lo(v3.w); a7 += bf_hi(v3.w);
  }
  for (; p < hi; ++p) {
    int s = csr_src[p];
    uint4 v = Ybf4[(size_t)s * 8 + l];
    a0 += bf_lo(v.x); a1 += bf_hi(v.x);
    a2 += bf_lo(v.y); a3 += bf_hi(v.y);
    a4 += bf_lo(v.z); a5 += bf_hi(v.z);
    a6 += bf_lo(v.w); a7 += bf_hi(v.w);
  }

  float d = dinv[nd];
  float4 b0 = *reinterpret_cast<const float4*>(bias + l * 8);
  float4 b1 = *reinterpret_cast<const float4*>(bias + l * 8 + 4);
  float4 o0, o1;
  o0.x = fmaf(d, a0, b0.x); o0.y = fmaf(d, a1, b0.y);
  o0.z = fmaf(d, a2, b0.z); o0.w = fmaf(d, a3, b0.w);
  o1.x = fmaf(d, a4, b1.x); o1.y = fmaf(d, a5, b1.y);
  o1.z = fmaf(d, a6, b1.z); o1.w = fmaf(d, a7, b1.w);
  o0.x = fmaxf(o0.x, 0.f); o0.y = fmaxf(o0.y, 0.f);
  o0.z = fmaxf(o0.z, 0.f); o0.w = fmaxf(o0.w, 0.f);
  o1.x = fmaxf(o1.x, 0.f); o1.y = fmaxf(o1.y, 0.f);
  o1.z = fmaxf(o1.z, 0.f); o1.w = fmaxf(o1.w, 0.f);
  float* hr = H + (size_t)nd * NCOL + l * 8;
  *reinterpret_cast<float4*>(hr) = o0;
  *reinterpret_cast<float4*>(hr + 4) = o1;
}

// ---------------- layer-2 aggregate fused with pooling (separate kernel) ----------------
// Same gather structure; instead of writing H, wave-reduce the 8 rows when
// the wave's nodes share one graph (batch sorted -> common case) and emit
// 64 atomicAdds per wave into pool[g]; else per-group atomics.

__global__ __launch_bounds__(256) void aggregate_pool(
    const int* __restrict__ rowptr, const int* __restrict__ csr_src,
    const uint4* __restrict__ Ybf4, const float* __restrict__ dinv,
    const float* __restrict__ bias, const int* __restrict__ batch,
    float* __restrict__ pool, int n) {
  int nd = (blockIdx.x * blockDim.x + threadIdx.x) >> 3;
  if (nd >= n) return;
  int l = threadIdx.x & 7;
  int lo = rowptr[nd], hi = rowptr[nd + 1];

  uint4 vs = Ybf4[(size_t)nd * 8 + l];
  float a0 = bf_lo(vs.x), a1 = bf_hi(vs.x);
  float a2 = bf_lo(vs.y), a3 = bf_hi(vs.y);
  float a4 = bf_lo(vs.z), a5 = bf_hi(vs.z);
  float a6 = bf_lo(vs.w), a7 = bf_hi(vs.w);

  int p = lo;
  for (; p + 3 < hi; p += 4) {
    int s0 = csr_src[p];
    int s1 = csr_src[p + 1];
    int s2 = csr_src[p + 2];
    int s3 = csr_src[p + 3];
    uint4 v0 = Ybf4[(size_t)s0 * 8 + l];
    uint4 v1 = Ybf4[(size_t)s1 * 8 + l];
    uint4 v2 = Ybf4[(size_t)s2 * 8 + l];
    uint4 v3 = Ybf4[(size_t)s3 * 8 + l];
    a0 += bf_lo(v0.x); a1 += bf_hi(v0.x);
    a2 += bf_lo(v0.y); a3 += bf_hi(v0.y);
    a4 += bf_lo(v0.z); a5 += bf_hi(v0.z);
    a6 += bf_lo(v0.w); a7 += bf_hi(v0.w);
    a0 += bf_lo(v1.x); a1 += bf_hi(v1.x);
    a2 += bf_lo(v1.y); a3 += bf_hi(v1.y);
    a4 += bf_lo(v1.z); a5 += bf_hi(v1.z);
    a6 += bf_lo(v1.w); a7 += bf_hi(v1.w);
    a0 += bf_lo(v2.x); a1 += bf_hi(v2.x);
    a2 += bf_lo(v2.y); a3 += bf_hi(v2.y);
    a4 += bf_lo(v2.z); a5 += bf_hi(v2.z);
    a6 += bf_lo(v2.w); a7 += bf_hi(v2.w);
    a0 += bf_lo(v3.x); a1 += bf_hi(v3.x);
    a2 += bf_lo(v3.y); a3 += bf_hi(v3.y);
    a4 += bf_lo(v3.z); a5 += bf_hi(v3.z);
    a6 += bf_lo(v3.w); a7 += bf_hi(v3.w);
  }
  for (; p < hi; ++p) {
    int s = csr_src[p];
    uint4 v = Ybf4[(size_t)s * 8 + l];
    a0 += bf_lo(v.x); a1 += bf_hi(v.x);
    a2 += bf_lo(v.y); a3 += bf_hi(v.y);
    a4 += bf_lo(v.z); a5 += bf_hi(v.z);
    a6 += bf_lo(v.w); a7 += bf_hi(v.w);
  }

  float d = dinv[nd];
  float4 b0 = *reinterpret_cast<const float4*>(bias + l * 8);
  float4 b1 = *reinterpret_cast<const float4*>(bias + l * 8 + 4);
  float4 o0, o1;
  o0.x = fmaf(d, a0, b0.x); o0.y = fmaf(d, a1, b0.y);
  o0.z = fmaf(d, a2, b0.z); o0.w = fmaf(d, a3, b0.w);
  o1.x = fmaf(d, a4, b1.x); o1.y = fmaf(d, a5, b1.y);
  o1.z = fmaf(d, a6, b1.z); o1.w = fmaf(d, a7, b1.w);

  int gg = batch[nd];
  int waveFirstNd = (blockIdx.x * blockDim.x + (threadIdx.x & ~63)) >> 3;
  bool full = (waveFirstNd + 8 <= n);
  int g0 = __builtin_amdgcn_readfirstlane(gg);
  bool uni = full && __all(gg == g0);
  if (uni) {
#pragma unroll
    for (int m = 8; m < 64; m <<= 1) {
      o0.x += __shfl_xor(o0.x, m); o0.y += __shfl_xor(o0.y, m);
      o0.z += __shfl_xor(o0.z, m); o0.w += __shfl_xor(o0.w, m);
      o1.x += __shfl_xor(o1.x, m); o1.y += __shfl_xor(o1.y, m);
      o1.z += __shfl_xor(o1.z, m); o1.w += __shfl_xor(o1.w, m);
    }
    if ((threadIdx.x & 63) < 8) {
      float* pr = pool + (size_t)g0 * NCOL + l * 8;
      atomicAdd(pr + 0, o0.x); atomicAdd(pr + 1, o0.y);
      atomicAdd(pr + 2, o0.z); atomicAdd(pr + 3, o0.w);
      atomicAdd(pr + 4, o1.x); atomicAdd(pr + 5, o1.y);
      atomicAdd(pr + 6, o1.z); atomicAdd(pr + 7, o1.w);
    }
  } else {
    float* pr = pool + (size_t)gg * NCOL + l * 8;
    atomicAdd(pr + 0, o0.x); atomicAdd(pr + 1, o0.y);
    atomicAdd(pr + 2, o0.z); atomicAdd(pr + 3, o0.w);
    atomicAdd(pr + 4, o1.x); atomicAdd(pr + 5, o1.y);
    atomicAdd(pr + 6, o1.z); atomicAdd(pr + 7, o1.w);
  }
}

// ---------------- final tiny GEMM: out = (pool/cnt) @ Wl + bl ----------------

__global__ void final_kernel(const float* __restrict__ pool, const int* __restrict__ startg,
                             const int* __restrict__ endg, const float* __restrict__ Wl,
                             const float* __restrict__ bl, float* __restrict__ out, int ng) {
  int t = threadIdx.x;
  if (t >= ng * 6) return;
  int g = t / 6, o = t % 6;
  float cntf = (float)(endg[g] - startg[g]);
  float inv = 1.0f / fmaxf(cntf, 1.0f);
  float s = 0.f;
#pragma unroll
  for (int c = 0; c < NCOL; ++c) s += pool[(size_t)g * NCOL + c] * Wl[c * 6 + o];
  out[t] = fmaf(s, inv, bl[o]);
}

// ---------------- launch ----------------

extern "C" void kernel_launch(void* const* d_in, const int* in_sizes, int n_in,
                              void* d_out, int out_size, void* d_ws, size_t ws_size,
                              hipStream_t stream) {
  const float* x    = (const float*)d_in[0];
  const int*   ei   = (const int*)d_in[1];
  const int*   batch= (const int*)d_in[2];
  const float* W1   = (const float*)d_in[3];
  const float* b1   = (const float*)d_in[4];
  const float* W2   = (const float*)d_in[5];
  const float* b2   = (const float*)d_in[6];
  const float* Wl   = (const float*)d_in[7];
  const float* bl   = (const float*)d_in[8];
  float* out = (float*)d_out;

  int n  = in_sizes[0] / 128;   // 100000
  int ne = in_sizes[1] / 2;     // 1600000
  int ng = out_size / 6;        // 64
  const int* srcI = ei;
  const int* dstI = ei + ne;

  int nb   = (n + 255) >> BSH;            // 391 buckets
  int nblk = (ne + EPB - 1) / EPB;        // 782 P1 blocks

  char* w = (char*)d_ws;
  size_t o = 0;
  auto take = [&](size_t bytes) -> char* {
    char* p = w + o;
    o = (o + bytes + 255) & ~(size_t)255;
    return p;
  };
  float*        dinv    = (float*)take((size_t)n * 4);
  int*          degi    = (int*)  take((size_t)n * 4);
  int*          rowptr  = (int*)  take((size_t)(n + 1) * 4);
  int*          csr_src = (int*)  take((size_t)ne * 4);
  unsigned int* ent     = (unsigned int*)take((size_t)ne * 4);
  int*          blockOff= (int*)  take((size_t)nblk * nb * 4);
  unsigned int* Ybf     = (unsigned int*)take((size_t)n * (NCOL / 2) * 4);
  float*        H       = (float*)take((size_t)n * NCOL * 4);
  float*        pool    = (float*)take(4096 * 4);
  int*          startg  = (int*)  take(64 * 4);
  int*          endg    = (int*)  take(64 * 4);
  int*          tsum    = (int*)  take(16384 * 4);
  int*          toff    = (int*)  take(16384 * 4);

  hipMemsetAsync(pool, 0, 4096 * 4, stream);
  hipMemsetAsync(startg, 0, 64 * 4, stream);
  hipMemsetAsync(endg, 0, 64 * 4, stream);

  int nb256 = (n + 255) / 256;
  int nthreads = (n + SCAN_C - 1) / SCAN_C;
  int nbScan = (nthreads + 255) / 256;

  // CSR build via two-phase LDS binning (all global writes coalesced)
  bin_p1<<<nblk, 256, 0, stream>>>(srcI, dstI, ent, blockOff, ne, nb);
  deg_bin<<<nb, 256, 0, stream>>>(ent, blockOff, degi, n, ne, nb, nblk);
  bounds_kernel<<<nb256, 256, 0, stream>>>(batch, startg, endg, n);
  dinv_kernel<<<nb256, 256, 0, stream>>>(degi, dinv, n);
  scan_part<<<nbScan, 256, 0, stream>>>(degi, tsum, n, nthreads);
  scan_mid<<<1, 1024, 0, stream>>>(tsum, toff, nthreads);
  scan_fill<<<nbScan, 256, 0, stream>>>(degi, toff, rowptr, n, nthreads);
  bin_p2<<<nb, 256, 0, stream>>>(ent, blockOff, rowptr, csr_src, n, ne, nb, nblk);

  int nbAgg = (n * 8 + 255) / 256;   // 8 lanes per node
  int nbGemm = (n + 63) / 64;

  // layer 1: Ybf = bf16((x@W1)*dinv) ; H = relu(dinv*(Y_self + sum Y[src]) + b1)
  gemm_mfma<128><<<nbGemm, 256, 0, stream>>>(x, W1, dinv, Ybf, n);
  aggregate_relu<<<nbAgg, 256, 0, stream>>>(rowptr, csr_src, (const uint4*)Ybf,
                                            dinv, b1, H, n);

  // layer 2: Ybf = bf16((H@W2)*dinv) ; pool[g] += dinv*(Y_self + sum Y[src]) + b2
  gemm_mfma<64><<<nbGemm, 256, 0, stream>>>(H, W2, dinv, Ybf, n);
  aggregate_pool<<<nbAgg, 256, 0, stream>>>(rowptr, csr_src, (const uint4*)Ybf,
                                            dinv, b2, batch, pool, n);

  // head (mean + tiny GEMM)
  final_kernel<<<1, 384, 0, stream>>>(pool, startg, endg, Wl, bl, out, ng);
}

// Round 20
// 211.461 us; speedup vs baseline: 1.4101x; 1.4093x over previous
//
#include <hip/hip_runtime.h>

#define NCOL 64
#define BSH 8                 // 256 dst nodes per bucket
#define NBMAX 512             // padded bucket count (scan width)
#define EPB 2048              // edges per P1 block
#define P2CAP 6144            // LDS out-stage entries (bucket avg 4096, +32 sigma)
#define NREP 8                // pool replicas (one per XCD)

typedef __attribute__((ext_vector_type(8))) short bf16x8;
typedef __attribute__((ext_vector_type(4))) float f32x4;

// ---------------- bf16 helpers (RNE pack, bit-shift unpack) ----------------

__device__ __forceinline__ float bf_lo(unsigned int v) { return __uint_as_float(v << 16); }
__device__ __forceinline__ float bf_hi(unsigned int v) { return __uint_as_float(v & 0xFFFF0000u); }
__device__ __forceinline__ unsigned short bfs(float x) {  // RNE f32->bf16 bits
  unsigned int u = __float_as_uint(x);
  u = (u + 0x7FFFu + ((u >> 16) & 1u)) >> 16;
  return (unsigned short)u;
}

// ---------------- P1: block-local counting sort of edges by dst bucket ----------------
// Entry pack: (dst&255)<<17 | src   (src < 2^17 on this problem: n = 100000)

__global__ __launch_bounds__(256) void bin_p1(const int* __restrict__ src,
                                              const int* __restrict__ dst,
                                              unsigned int* __restrict__ ent,
                                              int* __restrict__ blockOff,
                                              int ne, int nb) {
  __shared__ int hist[NBMAX];
  __shared__ int base[NBMAX];
  __shared__ int part[256];
  __shared__ unsigned int stage[EPB];
  int tid = threadIdx.x;
  int e0 = blockIdx.x * EPB;
  int cnt = min(EPB, ne - e0);

  for (int i = tid; i < NBMAX; i += 256) hist[i] = 0;
  __syncthreads();
  for (int i = tid; i < cnt; i += 256) {
    int d = dst[e0 + i];
    atomicAdd(&hist[d >> BSH], 1);
  }
  __syncthreads();

  int a0 = hist[2 * tid], a1 = hist[2 * tid + 1];
  int s = a0 + a1;
  part[tid] = s;
  __syncthreads();
  for (int d = 1; d < 256; d <<= 1) {
    int v = (tid >= d) ? part[tid - d] : 0;
    __syncthreads();
    part[tid] += v;
    __syncthreads();
  }
  int off = part[tid] - s;
  base[2 * tid] = off;
  base[2 * tid + 1] = off + a0;
  __syncthreads();

  for (int b = tid; b < nb; b += 256) blockOff[(size_t)blockIdx.x * nb + b] = base[b];
  for (int i = tid; i < NBMAX; i += 256) hist[i] = base[i];
  __syncthreads();

  for (int i = tid; i < cnt; i += 256) {
    int d = dst[e0 + i];
    int sv = src[e0 + i];
    unsigned int e = ((unsigned int)(d & ((1 << BSH) - 1)) << 17) | (unsigned int)sv;
    int p = atomicAdd(&hist[d >> BSH], 1);
    stage[p] = e;
  }
  __syncthreads();
  for (int i = tid; i < cnt; i += 256) ent[e0 + i] = stage[i];
}

// ---------------- degree from binned entries (LDS counters, coalesced writes) ----------------

__global__ __launch_bounds__(256) void deg_bin(const unsigned int* __restrict__ ent,
                                               const int* __restrict__ blockOff,
                                               int* __restrict__ degi,
                                               int n, int ne, int nb, int nblk) {
  __shared__ int cnt[256];
  int b = blockIdx.x;
  int tid = threadIdx.x;
  cnt[tid] = 0;
  __syncthreads();
  for (int blk = tid; blk < nblk; blk += 256) {
    int e0 = blk * EPB;
    int bcnt = min(EPB, ne - e0);
    int st = blockOff[(size_t)blk * nb + b];
    int en = (b + 1 < nb) ? blockOff[(size_t)blk * nb + b + 1] : bcnt;
    for (int i = st; i < en; ++i) {
      unsigned int e = ent[e0 + i];
      atomicAdd(&cnt[e >> 17], 1);
    }
  }
  __syncthreads();
  int node = (b << BSH) + tid;
  if (node < n) degi[node] = cnt[tid];
}

__global__ void dinv_kernel(const int* __restrict__ degi, float* __restrict__ dinv, int n) {
  int i = blockIdx.x * blockDim.x + threadIdx.x;
  if (i < n) dinv[i] = rsqrtf((float)degi[i] + 1.0f);
}

// ---------------- graph-run boundaries (batch is SORTED -> no atomics) ----------------

__global__ void bounds_kernel(const int* __restrict__ batch, int* __restrict__ startg,
                              int* __restrict__ endg, int n) {
  int i = blockIdx.x * blockDim.x + threadIdx.x;
  if (i >= n) return;
  int b = batch[i];
  if (i == 0) {
    startg[b] = 0;
  } else {
    int bp = batch[i - 1];
    if (b != bp) { startg[b] = i; endg[bp] = i; }
  }
  if (i == n - 1) endg[b] = n;
}

// ---------------- 3-pass exclusive scan of degrees -> rowptr[0..n] ----------------

#define SCAN_C 8

__global__ void scan_part(const int* __restrict__ degi, int* __restrict__ tsum,
                          int n, int nthreads) {
  int t = blockIdx.x * blockDim.x + threadIdx.x;
  if (t >= nthreads) return;
  int lo = t * SCAN_C, hi = min(lo + SCAN_C, n);
  int s = 0;
  for (int i = lo; i < hi; ++i) s += degi[i];
  tsum[t] = s;
}

__global__ void scan_mid(int* __restrict__ tsum, int* __restrict__ toff, int nthreads) {
  __shared__ int part[1024];
  int t = threadIdx.x;
  int chunk = (nthreads + 1023) >> 10;
  int lo = t * chunk, hi = min(lo + chunk, nthreads);
  int s = 0;
  for (int i = lo; i < hi; ++i) s += tsum[i];
  part[t] = s;
  __syncthreads();
  for (int d = 1; d < 1024; d <<= 1) {
    int v = (t >= d) ? part[t - d] : 0;
    __syncthreads();
    part[t] += v;
    __syncthreads();
  }
  int off = part[t] - s;
  for (int i = lo; i < hi; ++i) { toff[i] = off; off += tsum[i]; }
}

__global__ void scan_fill(const int* __restrict__ degi, const int* __restrict__ toff,
                          int* __restrict__ rowptr, int n, int nthreads) {
  int t = blockIdx.x * blockDim.x + threadIdx.x;
  if (t >= nthreads) return;
  int lo = t * SCAN_C, hi = min(lo + SCAN_C, n);
  int off = toff[t];
  for (int i = lo; i < hi; ++i) {
    rowptr[i] = off;
    off += degi[i];
  }
  if (hi == n) rowptr[n] = off;
}

// ---------------- P2: bucket-local LDS scatter -> node-grouped CSR ----------------

__global__ __launch_bounds__(256) void bin_p2(const unsigned int* __restrict__ ent,
                                              const int* __restrict__ blockOff,
                                              const int* __restrict__ rowptr,
                                              int* __restrict__ csr_src,
                                              int n, int ne, int nb, int nblk) {
  __shared__ int cur[256];
  __shared__ int outS[P2CAP];
  int b = blockIdx.x;
  int tid = threadIdx.x;
  int node0 = b << BSH;
  int node1 = min(node0 + 256, n);
  int bucketBase = rowptr[node0];
  int bucketCnt = rowptr[node1] - bucketBase;
  int node = node0 + tid;
  cur[tid] = (node < node1) ? (rowptr[node] - bucketBase) : 0;
  __syncthreads();
  for (int blk = tid; blk < nblk; blk += 256) {
    int e0 = blk * EPB;
    int bcnt = min(EPB, ne - e0);
    int st = blockOff[(size_t)blk * nb + b];
    int en = (b + 1 < nb) ? blockOff[(size_t)blk * nb + b + 1] : bcnt;
    for (int i = st; i < en; ++i) {
      unsigned int e = ent[e0 + i];
      int dL = e >> 17;
      int sv = (int)(e & 0x1FFFFu);
      int p = atomicAdd(&cur[dL], 1);
      if (p < P2CAP) outS[p] = sv;
      else csr_src[bucketBase + p] = sv;   // rare overflow fallback
    }
  }
  __syncthreads();
  int lim = min(bucketCnt, P2CAP);
  for (int i = tid; i < lim; i += 256) csr_src[bucketBase + i] = outS[i];
}

// ---------------- MFMA GEMM -> bf16 messages ----------------
// mfma_f32_16x16x32_bf16. Block = 64 rows x 64 cols, 4 waves; wave w owns
// cols 16w..16w+15 and 4 row-tiles of 16 (layouts per guide §3, m89).

template<int K>
__global__ __launch_bounds__(256, 8) void gemm_mfma(
    const float* __restrict__ X, const float* __restrict__ W,
    const float* __restrict__ dinv, unsigned int* __restrict__ Ybf, int n) {
  __shared__ unsigned short YS[64][64];
  int tid = threadIdx.x;
  int w = tid >> 6;          // wave id -> col group
  int l = tid & 63;
  int lr = l & 15;           // A-row within tile / B,D col
  int lk = l >> 4;           // k group
  int rows0 = blockIdx.x * 64;

  // B fragments (held in registers for the whole kernel)
  bf16x8 bfrag[K / 32];
#pragma unroll
  for (int s = 0; s < K / 32; ++s) {
#pragma unroll
    for (int j = 0; j < 8; ++j) {
      int k = s * 32 + lk * 8 + j;
      bfrag[s][j] = (short)bfs(W[(size_t)k * NCOL + 16 * w + lr]);
    }
  }

  f32x4 acc[4];
#pragma unroll
  for (int rt = 0; rt < 4; ++rt) acc[rt] = (f32x4){0.f, 0.f, 0.f, 0.f};

#pragma unroll
  for (int rt = 0; rt < 4; ++rt) {
    int row = min(rows0 + rt * 16 + lr, n - 1);
    const float* xr = X + (size_t)row * K + lk * 8;
#pragma unroll
    for (int s = 0; s < K / 32; ++s) {
      float4 x0 = *reinterpret_cast<const float4*>(xr + s * 32);
      float4 x1 = *reinterpret_cast<const float4*>(xr + s * 32 + 4);
      bf16x8 af;
      af[0] = (short)bfs(x0.x); af[1] = (short)bfs(x0.y);
      af[2] = (short)bfs(x0.z); af[3] = (short)bfs(x0.w);
      af[4] = (short)bfs(x1.x); af[5] = (short)bfs(x1.y);
      af[6] = (short)bfs(x1.z); af[7] = (short)bfs(x1.w);
      acc[rt] = __builtin_amdgcn_mfma_f32_16x16x32_bf16(af, bfrag[s], acc[rt], 0, 0, 0);
    }
  }

  // epilogue: scale by dinv, pack bf16 into LDS tile
#pragma unroll
  for (int rt = 0; rt < 4; ++rt) {
#pragma unroll
    for (int j = 0; j < 4; ++j) {
      int row = rt * 16 + lk * 4 + j;
      float d = dinv[min(rows0 + row, n - 1)];
      YS[row][16 * w + lr] = bfs(acc[rt][j] * d);
    }
  }
  __syncthreads();

  // coalesced copy: 64 rows x 8 uint4
  const uint4* ys4 = reinterpret_cast<const uint4*>(&YS[0][0]);
  for (int idx = tid; idx < 512; idx += 256) {
    int row = idx >> 3;
    int gr = rows0 + row;
    if (gr < n)
      reinterpret_cast<uint4*>(Ybf + (size_t)gr * 32)[idx & 7] = ys4[idx];
  }
}

// ---------------- layer-1 aggregate: H = relu(dinv*(self + sum) + b) ----------------
// (verbatim R17 structure)

__global__ __launch_bounds__(256) void aggregate_relu(
    const int* __restrict__ rowptr, const int* __restrict__ csr_src,
    const uint4* __restrict__ Ybf4, const float* __restrict__ dinv,
    const float* __restrict__ bias, float* __restrict__ H, int n) {
  int nd = (blockIdx.x * blockDim.x + threadIdx.x) >> 3;
  if (nd >= n) return;
  int l = threadIdx.x & 7;
  int lo = rowptr[nd], hi = rowptr[nd + 1];

  uint4 vs = Ybf4[(size_t)nd * 8 + l];
  float a0 = bf_lo(vs.x), a1 = bf_hi(vs.x);
  float a2 = bf_lo(vs.y), a3 = bf_hi(vs.y);
  float a4 = bf_lo(vs.z), a5 = bf_hi(vs.z);
  float a6 = bf_lo(vs.w), a7 = bf_hi(vs.w);

  int p = lo;
  for (; p + 3 < hi; p += 4) {
    int s0 = csr_src[p];
    int s1 = csr_src[p + 1];
    int s2 = csr_src[p + 2];
    int s3 = csr_src[p + 3];
    uint4 v0 = Ybf4[(size_t)s0 * 8 + l];
    uint4 v1 = Ybf4[(size_t)s1 * 8 + l];
    uint4 v2 = Ybf4[(size_t)s2 * 8 + l];
    uint4 v3 = Ybf4[(size_t)s3 * 8 + l];
    a0 += bf_lo(v0.x); a1 += bf_hi(v0.x);
    a2 += bf_lo(v0.y); a3 += bf_hi(v0.y);
    a4 += bf_lo(v0.z); a5 += bf_hi(v0.z);
    a6 += bf_lo(v0.w); a7 += bf_hi(v0.w);
    a0 += bf_lo(v1.x); a1 += bf_hi(v1.x);
    a2 += bf_lo(v1.y); a3 += bf_hi(v1.y);
    a4 += bf_lo(v1.z); a5 += bf_hi(v1.z);
    a6 += bf_lo(v1.w); a7 += bf_hi(v1.w);
    a0 += bf_lo(v2.x); a1 += bf_hi(v2.x);
    a2 += bf_lo(v2.y); a3 += bf_hi(v2.y);
    a4 += bf_lo(v2.z); a5 += bf_hi(v2.z);
    a6 += bf_lo(v2.w); a7 += bf_hi(v2.w);
    a0 += bf_lo(v3.x); a1 += bf_hi(v3.x);
    a2 += bf_lo(v3.y); a3 += bf_hi(v3.y);
    a4 += bf_lo(v3.z); a5 += bf_hi(v3.z);
    a6 += bf_lo(v3.w); a7 += bf_hi(v3.w);
  }
  for (; p < hi; ++p) {
    int s = csr_src[p];
    uint4 v = Ybf4[(size_t)s * 8 + l];
    a0 += bf_lo(v.x); a1 += bf_hi(v.x);
    a2 += bf_lo(v.y); a3 += bf_hi(v.y);
    a4 += bf_lo(v.z); a5 += bf_hi(v.z);
    a6 += bf_lo(v.w); a7 += bf_hi(v.w);
  }

  float d = dinv[nd];
  float4 b0 = *reinterpret_cast<const float4*>(bias + l * 8);
  float4 b1 = *reinterpret_cast<const float4*>(bias + l * 8 + 4);
  float4 o0, o1;
  o0.x = fmaf(d, a0, b0.x); o0.y = fmaf(d, a1, b0.y);
  o0.z = fmaf(d, a2, b0.z); o0.w = fmaf(d, a3, b0.w);
  o1.x = fmaf(d, a4, b1.x); o1.y = fmaf(d, a5, b1.y);
  o1.z = fmaf(d, a6, b1.z); o1.w = fmaf(d, a7, b1.w);
  o0.x = fmaxf(o0.x, 0.f); o0.y = fmaxf(o0.y, 0.f);
  o0.z = fmaxf(o0.z, 0.f); o0.w = fmaxf(o0.w, 0.f);
  o1.x = fmaxf(o1.x, 0.f); o1.y = fmaxf(o1.y, 0.f);
  o1.z = fmaxf(o1.z, 0.f); o1.w = fmaxf(o1.w, 0.f);
  float* hr = H + (size_t)nd * NCOL + l * 8;
  *reinterpret_cast<float4*>(hr) = o0;
  *reinterpret_cast<float4*>(hr + 4) = o1;
}

// ---------------- layer-2 aggregate fused with pooling ----------------
// Contention fix (R19 post-mortem): (1) block-level LDS reduction -> 64
// atomics per 32-node block (4x fewer); (2) 8x replicated pool indexed by
// blockIdx&7 -> atomics stay XCD-local, ~6 same-address conflicts instead
// of ~195 cross-XCD (the ~100us serial chain).

__global__ __launch_bounds__(256) void aggregate_pool(
    const int* __restrict__ rowptr, const int* __restrict__ csr_src,
    const uint4* __restrict__ Ybf4, const float* __restrict__ dinv,
    const float* __restrict__ bias, const int* __restrict__ batch,
    float* __restrict__ poolrep, int n) {
  __shared__ float poolS[4][64];
  __shared__ int gS[4];
  __shared__ int uniS[4];
  int tid = threadIdx.x;
  int nd = (blockIdx.x * blockDim.x + tid) >> 3;
  int w = tid >> 6;
  int l = tid & 7;
  bool active = nd < n;
  int ndc = active ? nd : (n - 1);
  int lo = rowptr[ndc];
  int hi = active ? rowptr[ndc + 1] : lo;

  uint4 vs = Ybf4[(size_t)ndc * 8 + l];
  float a0 = bf_lo(vs.x), a1 = bf_hi(vs.x);
  float a2 = bf_lo(vs.y), a3 = bf_hi(vs.y);
  float a4 = bf_lo(vs.z), a5 = bf_hi(vs.z);
  float a6 = bf_lo(vs.w), a7 = bf_hi(vs.w);

  int p = lo;
  for (; p + 3 < hi; p += 4) {
    int s0 = csr_src[p];
    int s1 = csr_src[p + 1];
    int s2 = csr_src[p + 2];
    int s3 = csr_src[p + 3];
    uint4 v0 = Ybf4[(size_t)s0 * 8 + l];
    uint4 v1 = Ybf4[(size_t)s1 * 8 + l];
    uint4 v2 = Ybf4[(size_t)s2 * 8 + l];
    uint4 v3 = Ybf4[(size_t)s3 * 8 + l];
    a0 += bf_lo(v0.x); a1 += bf_hi(v0.x);
    a2 += bf_lo(v0.y); a3 += bf_hi(v0.y);
    a4 += bf_lo(v0.z); a5 += bf_hi(v0.z);
    a6 += bf_lo(v0.w); a7 += bf_hi(v0.w);
    a0 += bf_lo(v1.x); a1 += bf_hi(v1.x);
    a2 += bf_lo(v1.y); a3 += bf_hi(v1.y);
    a4 += bf_lo(v1.z); a5 += bf_hi(v1.z);
    a6 += bf_lo(v1.w); a7 += bf_hi(v1.w);
    a0 += bf_lo(v2.x); a1 += bf_hi(v2.x);
    a2 += bf_lo(v2.y); a3 += bf_hi(v2.y);
    a4 += bf_lo(v2.z); a5 += bf_hi(v2.z);
    a6 += bf_lo(v2.w); a7 += bf_hi(v2.w);
    a0 += bf_lo(v3.x); a1 += bf_hi(v3.x);
    a2 += bf_lo(v3.y); a3 += bf_hi(v3.y);
    a4 += bf_lo(v3.z); a5 += bf_hi(v3.z);
    a6 += bf_lo(v3.w); a7 += bf_hi(v3.w);
  }
  for (; p < hi; ++p) {
    int s = csr_src[p];
    uint4 v = Ybf4[(size_t)s * 8 + l];
    a0 += bf_lo(v.x); a1 += bf_hi(v.x);
    a2 += bf_lo(v.y); a3 += bf_hi(v.y);
    a4 += bf_lo(v.z); a5 += bf_hi(v.z);
    a6 += bf_lo(v.w); a7 += bf_hi(v.w);
  }

  float d = dinv[ndc];
  float4 b0 = *reinterpret_cast<const float4*>(bias + l * 8);
  float4 b1 = *reinterpret_cast<const float4*>(bias + l * 8 + 4);
  float4 o0, o1;
  o0.x = fmaf(d, a0, b0.x); o0.y = fmaf(d, a1, b0.y);
  o0.z = fmaf(d, a2, b0.z); o0.w = fmaf(d, a3, b0.w);
  o1.x = fmaf(d, a4, b1.x); o1.y = fmaf(d, a5, b1.y);
  o1.z = fmaf(d, a6, b1.z); o1.w = fmaf(d, a7, b1.w);

  float* rep = poolrep + (size_t)(blockIdx.x & (NREP - 1)) * 4096;
  int gg = active ? batch[nd] : -1;
  int waveFirstNd = (blockIdx.x * blockDim.x + (tid & ~63)) >> 3;
  bool full = (waveFirstNd + 8 <= n);
  int g0 = __builtin_amdgcn_readfirstlane(gg);
  bool uni = full && __all(gg == g0);

  if (uni) {
    // reduce the wave's 8 node-rows into one row (lanes 0-7 hold it)
#pragma unroll
    for (int m = 8; m < 64; m <<= 1) {
      o0.x += __shfl_xor(o0.x, m); o0.y += __shfl_xor(o0.y, m);
      o0.z += __shfl_xor(o0.z, m); o0.w += __shfl_xor(o0.w, m);
      o1.x += __shfl_xor(o1.x, m); o1.y += __shfl_xor(o1.y, m);
      o1.z += __shfl_xor(o1.z, m); o1.w += __shfl_xor(o1.w, m);
    }
    if ((tid & 63) < 8) {
      *reinterpret_cast<float4*>(&poolS[w][l * 8]) = o0;
      *reinterpret_cast<float4*>(&poolS[w][l * 8 + 4]) = o1;
    }
    if ((tid & 63) == 0) { gS[w] = g0; uniS[w] = 1; }
  } else {
    if ((tid & 63) == 0) { gS[w] = -1; uniS[w] = 0; }
    if (active) {   // rare: per-node atomics
      float* pr = rep + (size_t)gg * NCOL + l * 8;
      atomicAdd(pr + 0, o0.x); atomicAdd(pr + 1, o0.y);
      atomicAdd(pr + 2, o0.z); atomicAdd(pr + 3, o0.w);
      atomicAdd(pr + 4, o1.x); atomicAdd(pr + 5, o1.y);
      atomicAdd(pr + 6, o1.z); atomicAdd(pr + 7, o1.w);
    }
  }
  __syncthreads();

  if (tid < 64) {
    bool bu = uniS[0] && uniS[1] && uniS[2] && uniS[3] &&
              gS[0] == gS[1] && gS[1] == gS[2] && gS[2] == gS[3];
    if (bu) {
      float s = poolS[0][tid] + poolS[1][tid] + poolS[2][tid] + poolS[3][tid];
      atomicAdd(&rep[(size_t)gS[0] * NCOL + tid], s);
    } else {
#pragma unroll
      for (int ww = 0; ww < 4; ++ww)
        if (uniS[ww]) atomicAdd(&rep[(size_t)gS[ww] * NCOL + tid], poolS[ww][tid]);
    }
  }
}

// ---------------- final: sum replicas, mean, tiny GEMM ----------------

__global__ void final_kernel(const float* __restrict__ poolrep,
                             const int* __restrict__ startg,
                             const int* __restrict__ endg, const float* __restrict__ Wl,
                             const float* __restrict__ bl, float* __restrict__ out, int ng) {
  __shared__ float poolL[4096];
  int t = threadIdx.x;
  for (int idx = t; idx < ng * NCOL; idx += blockDim.x) {
    float s = 0.f;
#pragma unroll
    for (int r = 0; r < NREP; ++r) s += poolrep[(size_t)r * 4096 + idx];
    poolL[idx] = s;
  }
  __syncthreads();
  if (t >= ng * 6) return;
  int g = t / 6, o = t % 6;
  float cntf = (float)(endg[g] - startg[g]);
  float inv = 1.0f / fmaxf(cntf, 1.0f);
  float s = 0.f;
#pragma unroll
  for (int c = 0; c < NCOL; ++c) s += poolL[g * NCOL + c] * Wl[c * 6 + o];
  out[t] = fmaf(s, inv, bl[o]);
}

// ---------------- launch ----------------

extern "C" void kernel_launch(void* const* d_in, const int* in_sizes, int n_in,
                              void* d_out, int out_size, void* d_ws, size_t ws_size,
                              hipStream_t stream) {
  const float* x    = (const float*)d_in[0];
  const int*   ei   = (const int*)d_in[1];
  const int*   batch= (const int*)d_in[2];
  const float* W1   = (const float*)d_in[3];
  const float* b1   = (const float*)d_in[4];
  const float* W2   = (const float*)d_in[5];
  const float* b2   = (const float*)d_in[6];
  const float* Wl   = (const float*)d_in[7];
  const float* bl   = (const float*)d_in[8];
  float* out = (float*)d_out;

  int n  = in_sizes[0] / 128;   // 100000
  int ne = in_sizes[1] / 2;     // 1600000
  int ng = out_size / 6;        // 64
  const int* srcI = ei;
  const int* dstI = ei + ne;

  int nb   = (n + 255) >> BSH;            // 391 buckets
  int nblk = (ne + EPB - 1) / EPB;        // 782 P1 blocks

  char* w = (char*)d_ws;
  size_t o = 0;
  auto take = [&](size_t bytes) -> char* {
    char* p = w + o;
    o = (o + bytes + 255) & ~(size_t)255;
    return p;
  };
  float*        dinv    = (float*)take((size_t)n * 4);
  int*          degi    = (int*)  take((size_t)n * 4);
  int*          rowptr  = (int*)  take((size_t)(n + 1) * 4);
  int*          csr_src = (int*)  take((size_t)ne * 4);
  unsigned int* ent     = (unsigned int*)take((size_t)ne * 4);
  int*          blockOff= (int*)  take((size_t)nblk * nb * 4);
  unsigned int* Ybf     = (unsigned int*)take((size_t)n * (NCOL / 2) * 4);
  float*        H       = (float*)take((size_t)n * NCOL * 4);
  float*        poolrep = (float*)take((size_t)NREP * 4096 * 4);
  int*          startg  = (int*)  take(64 * 4);
  int*          endg    = (int*)  take(64 * 4);
  int*          tsum    = (int*)  take(16384 * 4);
  int*          toff    = (int*)  take(16384 * 4);

  hipMemsetAsync(poolrep, 0, (size_t)NREP * 4096 * 4, stream);
  hipMemsetAsync(startg, 0, 64 * 4, stream);
  hipMemsetAsync(endg, 0, 64 * 4, stream);

  int nb256 = (n + 255) / 256;
  int nthreads = (n + SCAN_C - 1) / SCAN_C;
  int nbScan = (nthreads + 255) / 256;

  // CSR build via two-phase LDS binning (all global writes coalesced)
  bin_p1<<<nblk, 256, 0, stream>>>(srcI, dstI, ent, blockOff, ne, nb);
  deg_bin<<<nb, 256, 0, stream>>>(ent, blockOff, degi, n, ne, nb, nblk);
  bounds_kernel<<<nb256, 256, 0, stream>>>(batch, startg, endg, n);
  dinv_kernel<<<nb256, 256, 0, stream>>>(degi, dinv, n);
  scan_part<<<nbScan, 256, 0, stream>>>(degi, tsum, n, nthreads);
  scan_mid<<<1, 1024, 0, stream>>>(tsum, toff, nthreads);
  scan_fill<<<nbScan, 256, 0, stream>>>(degi, toff, rowptr, n, nthreads);
  bin_p2<<<nb, 256, 0, stream>>>(ent, blockOff, rowptr, csr_src, n, ne, nb, nblk);

  int nbAgg = (n * 8 + 255) / 256;   // 8 lanes per node
  int nbGemm = (n + 63) / 64;

  // layer 1: Ybf = bf16((x@W1)*dinv) ; H = relu(dinv*(Y_self + sum Y[src]) + b1)
  gemm_mfma<128><<<nbGemm, 256, 0, stream>>>(x, W1, dinv, Ybf, n);
  aggregate_relu<<<nbAgg, 256, 0, stream>>>(rowptr, csr_src, (const uint4*)Ybf,
                                            dinv, b1, H, n);

  // layer 2: Ybf = bf16((H@W2)*dinv) ; poolrep += dinv*(Y_self + sum Y[src]) + b2
  gemm_mfma<64><<<nbGemm, 256, 0, stream>>>(H, W2, dinv, Ybf, n);
  aggregate_pool<<<nbAgg, 256, 0, stream>>>(rowptr, csr_src, (const uint4*)Ybf,
                                            dinv, b2, batch, poolrep, n);

  // head (replica-sum + mean + tiny GEMM)
  final_kernel<<<1, 384, 0, stream>>>(poolrep, startg, endg, Wl, bl, out, ng);
}